// Round 14
// baseline (26146.576 us; speedup 1.0000x reference)
//
#include <hip/hip_runtime.h>
#include <math.h>

#define H 768
#define SEQ 512
#define BATCH 8
#define NHEADS 8
#define DHEAD 96
#define FFDIM 3072
#define NLAYERS 12
#define NTOK (BATCH*SEQ)   // 4096

// ---------------------------------------------------------------------------
// Tiled GEMM: C[M,N] = act(A[M,K] @ W[K,N] + bias[N]); all-f64 FMA chain.
// BITWISE-identical outputs to round-13 (per-element k-chain unchanged);
// the only change is thread->element ownership: each thread's 8 A-rows are
// m = ty + 16*i (stride-16) instead of ty*8+i (consecutive). This turns the
// 8-way-conflicted A-fragment read (lane word-addr 16*ty+4j -> 2 bank groups)
// into conflict-free ds_read_b64 (word-addr 2*ty -> 16 distinct bank pairs).
// BM=128, BN=64, BK=32, 256 thr, 8x4 micro-tile.
// ---------------------------------------------------------------------------
template<typename TA, typename TC, int ACT>
__global__ __launch_bounds__(256) void gemm64(
    const TA* __restrict__ A, const float* __restrict__ W,
    const float* __restrict__ bias, TC* __restrict__ C,
    int M, int N, int K)
{
    __shared__ double As[32][128];   // [k][m]  32 KB
    __shared__ float  Bs[32][64];    // [k][n]   8 KB

    const int m0 = blockIdx.y * 128;
    const int n0 = blockIdx.x * 64;
    const int t  = threadIdx.x;
    const int tx = t & 15;           // n group (4 cols)
    const int ty = t >> 4;           // m lane base; thread's rows m = ty + 16*i

    const int arow = t >> 1;
    const int kh   = (t & 1) << 4;
    const TA* ap = A + (size_t)(m0 + arow) * K + kh;

    const int bk  = t >> 4;
    const int bnq = t & 15;

    double acc[8][4];
    #pragma unroll
    for (int i = 0; i < 8; ++i)
        #pragma unroll
        for (int j = 0; j < 4; ++j) acc[i][j] = 0.0;

    for (int k0 = 0; k0 < K; k0 += 32) {
        #pragma unroll
        for (int j = 0; j < 16; ++j)
            As[kh + j][arow] = (double)ap[k0 + j];
        *(float4*)&Bs[bk][bnq << 2] =
            *(const float4*)(W + (size_t)(k0 + bk) * N + n0 + (bnq << 2));
        *(float4*)&Bs[bk + 16][bnq << 2] =
            *(const float4*)(W + (size_t)(k0 + bk + 16) * N + n0 + (bnq << 2));
        __syncthreads();

        #pragma unroll
        for (int k = 0; k < 32; ++k) {
            double ar[8];
            #pragma unroll
            for (int i = 0; i < 8; ++i)
                ar[i] = As[k][ty + (i << 4)];     // conflict-free (bank 2*ty)
            float4 bf = *(const float4*)&Bs[k][tx << 2];
            double b0 = (double)bf.x, b1 = (double)bf.y;
            double b2 = (double)bf.z, b3 = (double)bf.w;
            #pragma unroll
            for (int i = 0; i < 8; ++i) {
                acc[i][0] = fma(ar[i], b0, acc[i][0]);
                acc[i][1] = fma(ar[i], b1, acc[i][1]);
                acc[i][2] = fma(ar[i], b2, acc[i][2]);
                acc[i][3] = fma(ar[i], b3, acc[i][3]);
            }
        }
        __syncthreads();
    }

    const float* bp = bias + n0 + (tx << 2);
    double bb[4] = {(double)bp[0], (double)bp[1], (double)bp[2], (double)bp[3]};
    #pragma unroll
    for (int i = 0; i < 8; ++i) {
        int row = m0 + ty + (i << 4);
        #pragma unroll
        for (int j = 0; j < 4; ++j) {
            double v = acc[i][j] + bb[j];
            if (ACT) v = v > 0.0 ? v : 0.0;
            C[(size_t)row * N + n0 + (tx << 2) + j] = (TC)v;
        }
    }
}

// ---------------------------------------------------------------------------
// Encoder: hidden64 = relu(features[4096,20] @ w_enc[20,768] + b_enc)
// ---------------------------------------------------------------------------
__global__ __launch_bounds__(256) void encoder_kernel(
    const float* __restrict__ feats, const float* __restrict__ w,
    const float* __restrict__ b, double* __restrict__ out)
{
    __shared__ float f[20];
    const int row = blockIdx.x;
    const int t = threadIdx.x;
    if (t < 20) f[t] = feats[(size_t)row * 20 + t];
    __syncthreads();
    #pragma unroll
    for (int j = 0; j < 3; ++j) {
        int col = t + (j << 8);
        double s = (double)b[col];
        #pragma unroll
        for (int k = 0; k < 20; ++k) s += (double)f[k] * (double)w[k * H + col];
        out[(size_t)row * H + col] = s > 0.0 ? s : 0.0;
    }
}

// ---------------------------------------------------------------------------
// Attention — BITWISE-identical compute to rounds 7/13 (passing). f32 LDS
// staging (exact bits), f64 FMA sequence (d+=2 pairs; PV fma order 0..5).
// Layout-only change vs R13: Ss padded [16][512] -> [16][528] (512%32==0 put
// a wave's 4 r-rows on one bank => 4-way on every Ss access; 528%32==16
// leaves only r/r+2 aliasing = 2-way = free).
// ---------------------------------------------------------------------------
__global__ __launch_bounds__(256) void attn_kernel(
    const float* __restrict__ qkv, float* __restrict__ ctx)
{
    const int bid = blockIdx.x;
    const int qt = bid & 31;
    const int h  = (bid >> 5) & 7;
    const int b  = bid >> 8;
    const int q0 = qt * 16;
    const int t  = threadIdx.x;

    __shared__ float Qs[16][98];     //  6.3 KB (pad 98)
    __shared__ float KVs[32][100];   // 12.8 KB
    __shared__ float Ss[16][528];    // 33.8 KB (pad 528)

    const size_t base = ((size_t)b * SEQ) * (3 * H) + h * DHEAD;

    for (int i = t; i < 16 * 96; i += 256) {
        int r = i / 96, d = i % 96;
        Qs[r][d] = qkv[base + (size_t)(q0 + r) * (3 * H) + d];
    }
    __syncthreads();

    const int r  = t >> 4;
    const int kk = t & 15;
    const double scale = 0.10206207261596575;  // 1/sqrt(96)

    for (int kt = 0; kt < SEQ; kt += 32) {
        for (int i = t; i < 32 * 96; i += 256) {
            int rr = i / 96, d = i % 96;
            KVs[rr][d] = qkv[base + H + (size_t)(kt + rr) * (3 * H) + d];
        }
        __syncthreads();
        double s0 = 0.0, s1 = 0.0;
        #pragma unroll
        for (int d = 0; d < 96; d += 2) {
            float2 qf = *(const float2*)&Qs[r][d];
            float2 ka = *(const float2*)&KVs[kk][d];
            float2 kb = *(const float2*)&KVs[kk + 16][d];
            double qx = (double)qf.x, qy = (double)qf.y;
            s0 = fma(qx, (double)ka.x, s0); s0 = fma(qy, (double)ka.y, s0);
            s1 = fma(qx, (double)kb.x, s1); s1 = fma(qy, (double)kb.y, s1);
        }
        Ss[r][kt + kk]      = (float)(s0 * scale);
        Ss[r][kt + kk + 16] = (float)(s1 * scale);
        __syncthreads();
    }

    // softmax over row r (16 lanes per row, same wave) — verbatim round 7
    float mx = -1e30f;
    for (int j = 0; j < 32; ++j) mx = fmaxf(mx, Ss[r][kk + 16 * j]);
    #pragma unroll
    for (int o = 1; o < 16; o <<= 1) mx = fmaxf(mx, __shfl_xor(mx, o));
    double sum = 0.0;
    for (int j = 0; j < 32; ++j) {
        double e = exp((double)Ss[r][kk + 16 * j] - (double)mx);
        Ss[r][kk + 16 * j] = (float)e;
        sum += e;
    }
    #pragma unroll
    for (int o = 1; o < 16; o <<= 1) sum += __shfl_xor(sum, o);
    const double inv = 1.0 / sum;

    const int dd = kk * 6;
    double acc[6] = {};
    for (int kt = 0; kt < SEQ; kt += 32) {
        __syncthreads();
        for (int i = t; i < 32 * 96; i += 256) {
            int rr = i / 96, d = i % 96;
            KVs[rr][d] = qkv[base + 2 * H + (size_t)(kt + rr) * (3 * H) + d];
        }
        __syncthreads();
        for (int k = 0; k < 32; ++k) {
            double p = (double)Ss[r][kt + k];
            float2 v0 = *(const float2*)&KVs[k][dd];
            float2 v1 = *(const float2*)&KVs[k][dd + 2];
            float2 v2 = *(const float2*)&KVs[k][dd + 4];
            acc[0] = fma(p, (double)v0.x, acc[0]);
            acc[1] = fma(p, (double)v0.y, acc[1]);
            acc[2] = fma(p, (double)v1.x, acc[2]);
            acc[3] = fma(p, (double)v1.y, acc[3]);
            acc[4] = fma(p, (double)v2.x, acc[4]);
            acc[5] = fma(p, (double)v2.y, acc[5]);
        }
    }
    float* crow = ctx + ((size_t)(b * SEQ + q0 + r)) * H + h * DHEAD + dd;
    #pragma unroll
    for (int j = 0; j < 6; ++j) crow[j] = (float)(acc[j] * inv);
}

// ---------------------------------------------------------------------------
// hidden64 = LayerNorm(hidden64 + x64) * g + b   (all f64)
// ---------------------------------------------------------------------------
__global__ __launch_bounds__(256) void add_ln_kernel(
    double* __restrict__ hid, const double* __restrict__ x,
    const float* __restrict__ g, const float* __restrict__ bb)
{
    __shared__ double red[4];
    const int row = blockIdx.x;
    const int t = threadIdx.x;
    const size_t off = (size_t)row * H;

    double v[3]; double s = 0.0;
    #pragma unroll
    for (int j = 0; j < 3; ++j) {
        int c = t + (j << 8);
        v[j] = hid[off + c] + x[off + c];
        s += v[j];
    }
    #pragma unroll
    for (int o = 1; o < 64; o <<= 1) s += __shfl_xor(s, o);
    if ((t & 63) == 0) red[t >> 6] = s;
    __syncthreads();
    const double mu = (red[0] + red[1] + red[2] + red[3]) * (1.0 / H);
    __syncthreads();

    double q = 0.0;
    #pragma unroll
    for (int j = 0; j < 3; ++j) { double d = v[j] - mu; q += d * d; }
    #pragma unroll
    for (int o = 1; o < 64; o <<= 1) q += __shfl_xor(q, o);
    if ((t & 63) == 0) red[t >> 6] = q;
    __syncthreads();
    const double var = (red[0] + red[1] + red[2] + red[3]) * (1.0 / H);
    const double inv = 1.0 / sqrt(var + 1e-5);

    #pragma unroll
    for (int j = 0; j < 3; ++j) {
        int c = t + (j << 8);
        hid[off + c] = (v[j] - mu) * inv * (double)g[c] + (double)bb[c];
    }
}

// ---------------------------------------------------------------------------
// angles64 = t2[4096,768](f32) @ wa2[768,3] + ba2, f64 accumulate/store
// ---------------------------------------------------------------------------
__global__ __launch_bounds__(64) void angles_kernel(
    const float* __restrict__ T2, const float* __restrict__ wa2,
    const float* __restrict__ ba2, double* __restrict__ out)
{
    const int row = blockIdx.x;
    const int lane = threadIdx.x;
    const float* trow = T2 + (size_t)row * H;
    double p0 = 0.0, p1 = 0.0, p2 = 0.0;
    for (int d = lane; d < H; d += 64) {
        double v = (double)trow[d];
        p0 += v * (double)wa2[d * 3 + 0];
        p1 += v * (double)wa2[d * 3 + 1];
        p2 += v * (double)wa2[d * 3 + 2];
    }
    #pragma unroll
    for (int o = 1; o < 64; o <<= 1) {
        p0 += __shfl_xor(p0, o); p1 += __shfl_xor(p1, o); p2 += __shfl_xor(p2, o);
    }
    if (lane == 0) {
        out[(size_t)row * 3 + 0] = p0 + (double)ba2[0];
        out[(size_t)row * 3 + 1] = p1 + (double)ba2[1];
        out[(size_t)row * 3 + 2] = p2 + (double)ba2[2];
    }
}

// ---------------------------------------------------------------------------
// Sequential coordinate build — VERBATIM rounds 7/13 (passing): STRICT
// float32, non-fused IEEE ops, left-to-right order, fp32 carry, IN-LOOP trig
// via (float)cos((double)x). One thread per batch.
// ---------------------------------------------------------------------------
__device__ __forceinline__ float cr_cosf(float x) { return (float)cos((double)x); }
__device__ __forceinline__ float cr_sinf(float x) { return (float)sin((double)x); }

__global__ void coords_kernel(const float* __restrict__ dist,
                              const float* __restrict__ ang,
                              float* __restrict__ out)
{
    const int b = threadIdx.x;
    if (b >= BATCH) return;

    const double ba = 2.0943951023931953;   // deg2rad(120)
    const float c2x = (float)(3.8 + 3.8 * cos(ba));
    const float c2y = (float)(3.8 * sin(ba));

    float p1[3] = {c2x, c2y, 0.f};
    float p2[3] = {3.8f, 0.f, 0.f};
    float p3[3] = {0.f, 0.f, 0.f};
    float* ob = out + (size_t)b * SEQ * 3;
    ob[0] = 0.f;  ob[1] = 0.f;  ob[2] = 0.f;
    ob[3] = 3.8f; ob[4] = 0.f;  ob[5] = 0.f;
    ob[6] = c2x;  ob[7] = c2y;  ob[8] = 0.f;

    for (int i = 3; i < SEQ; ++i) {
        float r  = dist[((size_t)(b * SEQ) + i) * H + (i - 1)];
        float th = ang[((size_t)(b * SEQ) + i) * 3 + 1];
        float ch = ang[((size_t)(b * SEQ) + i) * 3 + 2];

        float e1x = __fsub_rn(p1[0], p2[0]);
        float e1y = __fsub_rn(p1[1], p2[1]);
        float e1z = __fsub_rn(p1[2], p2[2]);
        float n = __fsqrt_rn(__fadd_rn(__fadd_rn(__fmul_rn(e1x, e1x),
                 __fmul_rn(e1y, e1y)), __fmul_rn(e1z, e1z)));
        e1x = __fdiv_rn(e1x, n); e1y = __fdiv_rn(e1y, n); e1z = __fdiv_rn(e1z, n);

        float ux = __fsub_rn(p3[0], p2[0]);
        float uy = __fsub_rn(p3[1], p2[1]);
        float uz = __fsub_rn(p3[2], p2[2]);
        n = __fsqrt_rn(__fadd_rn(__fadd_rn(__fmul_rn(ux, ux),
            __fmul_rn(uy, uy)), __fmul_rn(uz, uz)));
        ux = __fdiv_rn(ux, n); uy = __fdiv_rn(uy, n); uz = __fdiv_rn(uz, n);

        float e3x = __fsub_rn(__fmul_rn(e1y, uz), __fmul_rn(e1z, uy));
        float e3y = __fsub_rn(__fmul_rn(e1z, ux), __fmul_rn(e1x, uz));
        float e3z = __fsub_rn(__fmul_rn(e1x, uy), __fmul_rn(e1y, ux));
        n = __fsqrt_rn(__fadd_rn(__fadd_rn(__fmul_rn(e3x, e3x),
            __fmul_rn(e3y, e3y)), __fmul_rn(e3z, e3z)));
        e3x = __fdiv_rn(e3x, n); e3y = __fdiv_rn(e3y, n); e3z = __fdiv_rn(e3z, n);

        float e2x = __fsub_rn(__fmul_rn(e3y, e1z), __fmul_rn(e3z, e1y));
        float e2y = __fsub_rn(__fmul_rn(e3z, e1x), __fmul_rn(e3x, e1z));
        float e2z = __fsub_rn(__fmul_rn(e3x, e1y), __fmul_rn(e3y, e1x));

        float ct = cr_cosf(th), st = cr_sinf(th);
        float cc = cr_cosf(ch), sc = cr_sinf(ch);
        float A   = __fmul_rn(r, ct);
        float rst = __fmul_rn(r, st);
        float Bc  = __fmul_rn(rst, cc);
        float Cc  = __fmul_rn(rst, sc);

        float px = __fadd_rn(__fadd_rn(__fadd_rn(p1[0], __fmul_rn(A, e1x)),
                   __fmul_rn(Bc, e2x)), __fmul_rn(Cc, e3x));
        float py = __fadd_rn(__fadd_rn(__fadd_rn(p1[1], __fmul_rn(A, e1y)),
                   __fmul_rn(Bc, e2y)), __fmul_rn(Cc, e3y));
        float pz = __fadd_rn(__fadd_rn(__fadd_rn(p1[2], __fmul_rn(A, e1z)),
                   __fmul_rn(Bc, e2z)), __fmul_rn(Cc, e3z));

        float* op = ob + (size_t)i * 3;
        op[0] = px; op[1] = py; op[2] = pz;
        p3[0] = p2[0]; p3[1] = p2[1]; p3[2] = p2[2];
        p2[0] = p1[0]; p2[1] = p1[1]; p2[2] = p1[2];
        p1[0] = px;    p1[1] = py;    p1[2] = pz;
    }
}

// ---------------------------------------------------------------------------
__global__ void cast64to32_kernel(const double* __restrict__ src,
                                  float* __restrict__ dst, size_t n)
{
    size_t i = (size_t)blockIdx.x * blockDim.x + threadIdx.x;
    size_t stride = (size_t)gridDim.x * blockDim.x;
    for (; i < n; i += stride) dst[i] = (float)src[i];
}

// ---------------------------------------------------------------------------
extern "C" void kernel_launch(void* const* d_in, const int* in_sizes, int n_in,
                              void* d_out, int out_size, void* d_ws, size_t ws_size,
                              hipStream_t stream)
{
    const float* features = (const float*)d_in[0];
    const float* w_enc = (const float*)d_in[1];
    const float* b_enc = (const float*)d_in[2];
    const float* wqkv  = (const float*)d_in[3];
    const float* bqkv  = (const float*)d_in[4];
    const float* wo    = (const float*)d_in[5];
    const float* bo    = (const float*)d_in[6];
    const float* ln1_g = (const float*)d_in[7];
    const float* ln1_b = (const float*)d_in[8];
    const float* w1    = (const float*)d_in[9];
    const float* b1    = (const float*)d_in[10];
    const float* w2    = (const float*)d_in[11];
    const float* b2    = (const float*)d_in[12];
    const float* ln2_g = (const float*)d_in[13];
    const float* ln2_b = (const float*)d_in[14];
    const float* wd1   = (const float*)d_in[15];
    const float* bd1   = (const float*)d_in[16];
    const float* wd2   = (const float*)d_in[17];
    const float* bd2   = (const float*)d_in[18];
    const float* wa1   = (const float*)d_in[19];
    const float* ba1   = (const float*)d_in[20];
    const float* wa2   = (const float*)d_in[21];
    const float* ba2   = (const float*)d_in[22];

    // workspace: hidden64 | tmp64 | dist64 | ang64 | bigF | ctxF  (round-7 layout)
    char* wp = (char*)d_ws;
    double* hidden64 = (double*)wp;                       wp += (size_t)NTOK * H * 8;
    double* tmp64    = (double*)wp;                       wp += (size_t)NTOK * H * 8;
    double* dist64   = (double*)wp;                       wp += (size_t)NTOK * H * 8;
    double* ang64    = (double*)wp;                       wp += (size_t)NTOK * 3 * 8;
    float*  bigF     = (float*)wp;                        wp += (size_t)NTOK * FFDIM * 4;
    float*  ctxF     = (float*)wp;

    float* out_dist   = (float*)d_out;                       // [B,S,H]
    float* out_ang    = out_dist + (size_t)NTOK * H;         // [B,S,3]
    float* out_coord  = out_ang + (size_t)NTOK * 3;          // [B,S,3]
    float* out_hidden = out_coord + (size_t)NTOK * 3;        // [B,S,H]

    encoder_kernel<<<NTOK, 256, 0, stream>>>(features, w_enc, b_enc, hidden64);

    for (int l = 0; l < NLAYERS; ++l) {
        gemm64<double, float, 0><<<dim3(3 * H / 64, NTOK / 128), 256, 0, stream>>>(
            hidden64, wqkv + (size_t)l * H * 3 * H, bqkv + (size_t)l * 3 * H,
            bigF, NTOK, 3 * H, H);
        attn_kernel<<<BATCH * NHEADS * (SEQ / 16), 256, 0, stream>>>(bigF, ctxF);
        gemm64<float, double, 0><<<dim3(H / 64, NTOK / 128), 256, 0, stream>>>(
            ctxF, wo + (size_t)l * H * H, bo + (size_t)l * H, tmp64, NTOK, H, H);
        add_ln_kernel<<<NTOK, 256, 0, stream>>>(hidden64, tmp64,
            ln1_g + (size_t)l * H, ln1_b + (size_t)l * H);
        gemm64<double, float, 1><<<dim3(FFDIM / 64, NTOK / 128), 256, 0, stream>>>(
            hidden64, w1 + (size_t)l * H * FFDIM, b1 + (size_t)l * FFDIM,
            bigF, NTOK, FFDIM, H);
        gemm64<float, double, 0><<<dim3(H / 64, NTOK / 128), 256, 0, stream>>>(
            bigF, w2 + (size_t)l * FFDIM * H, b2 + (size_t)l * H, tmp64, NTOK, H, FFDIM);
        add_ln_kernel<<<NTOK, 256, 0, stream>>>(hidden64, tmp64,
            ln2_g + (size_t)l * H, ln2_b + (size_t)l * H);
    }

    // distances head
    gemm64<double, float, 1><<<dim3(H / 64, NTOK / 128), 256, 0, stream>>>(
        hidden64, wd1, bd1, ctxF, NTOK, H, H);
    gemm64<float, double, 0><<<dim3(H / 64, NTOK / 128), 256, 0, stream>>>(
        ctxF, wd2, bd2, dist64, NTOK, H, H);
    // angles head
    gemm64<double, float, 1><<<dim3(H / 64, NTOK / 128), 256, 0, stream>>>(
        hidden64, wa1, ba1, ctxF, NTOK, H, H);
    angles_kernel<<<NTOK, 64, 0, stream>>>(ctxF, wa2, ba2, ang64);

    // fp32 outputs first; coords consumes those exact fp32 values (in-loop trig)
    cast64to32_kernel<<<2048, 256, 0, stream>>>(dist64, out_dist, (size_t)NTOK * H);
    cast64to32_kernel<<<48, 256, 0, stream>>>(ang64, out_ang, (size_t)NTOK * 3);
    coords_kernel<<<1, 64, 0, stream>>>(out_dist, out_ang, out_coord);
    cast64to32_kernel<<<2048, 256, 0, stream>>>(hidden64, out_hidden, (size_t)NTOK * H);
}

// Round 15
// 25340.115 us; speedup vs baseline: 1.0318x; 1.0318x over previous
//
#include <hip/hip_runtime.h>
#include <math.h>

#define H 768
#define SEQ 512
#define BATCH 8
#define NHEADS 8
#define DHEAD 96
#define FFDIM 3072
#define NLAYERS 12
#define NTOK (BATCH*SEQ)   // 4096

template<typename T> struct vec2;
template<> struct vec2<double> { using type = double2; };
template<> struct vec2<float>  { using type = float2;  };

// ---------------------------------------------------------------------------
// Tiled GEMM: C[M,N] = act(A[M,K] @ W[K,N] + bias[N]); all-f64 FMA chain.
// Compute loop + C-write VERBATIM round-13 (passing, bit-exact). Only the
// A-staging changed: COALESCED transpose. Thread owns a 64B row segment
// (m = t>>2 + 64i, k-off 8*(t&3)), loads 4x double2/float2, writes 8 scalar
// LDS words (banks 2m%32 -> 16 banks x 4 lanes = 4-way, ~free). Same values
// land in the same As[k][m] slots (f32->f64 cvt exact) => outputs bitwise
// identical to R13.  BM=128, BN=64, BK=32, 256 thr, 8x4 micro-tile.
// ---------------------------------------------------------------------------
template<typename TA, typename TC, int ACT>
__global__ __launch_bounds__(256) void gemm64(
    const TA* __restrict__ A, const float* __restrict__ W,
    const float* __restrict__ bias, TC* __restrict__ C,
    int M, int N, int K)
{
    __shared__ double As[32][128];   // [k][m]  32 KB
    __shared__ float  Bs[32][64];    // [k][n]   8 KB

    const int m0 = blockIdx.y * 128;
    const int n0 = blockIdx.x * 64;
    const int t  = threadIdx.x;
    const int tx = t & 15;           // n group (4 cols)
    const int ty = t >> 4;           // m group (8 rows, consecutive: R13 map)

    const int sr2 = t >> 2;          // staging row base 0..63
    const int sc2 = t & 3;           // staging k-segment 0..3 (8 doubles each)

    const int bk  = t >> 4;
    const int bnq = t & 15;

    using TA2 = typename vec2<TA>::type;

    double acc[8][4];
    #pragma unroll
    for (int i = 0; i < 8; ++i)
        #pragma unroll
        for (int j = 0; j < 4; ++j) acc[i][j] = 0.0;

    for (int k0 = 0; k0 < K; k0 += 32) {
        // A staging: coalesced global (256B contiguous per row across 4 lanes),
        // transposing LDS writes at 4-way (free-ish)
        #pragma unroll
        for (int i = 0; i < 2; ++i) {
            int m = sr2 + (i << 6);
            const TA* src = A + (size_t)(m0 + m) * K + k0 + (sc2 << 3);
            #pragma unroll
            for (int j = 0; j < 4; ++j) {
                TA2 v = *(const TA2*)(src + (j << 1));
                As[(sc2 << 3) + (j << 1) + 0][m] = (double)v.x;
                As[(sc2 << 3) + (j << 1) + 1][m] = (double)v.y;
            }
        }
        *(float4*)&Bs[bk][bnq << 2] =
            *(const float4*)(W + (size_t)(k0 + bk) * N + n0 + (bnq << 2));
        *(float4*)&Bs[bk + 16][bnq << 2] =
            *(const float4*)(W + (size_t)(k0 + bk + 16) * N + n0 + (bnq << 2));
        __syncthreads();

        #pragma unroll
        for (int k = 0; k < 32; ++k) {
            double ar[8];
            #pragma unroll
            for (int j = 0; j < 4; ++j)
                *(double2*)&ar[j << 1] = *(const double2*)&As[k][(ty << 3) + (j << 1)];
            float4 bf = *(const float4*)&Bs[k][tx << 2];
            double b0 = (double)bf.x, b1 = (double)bf.y;
            double b2 = (double)bf.z, b3 = (double)bf.w;
            #pragma unroll
            for (int i = 0; i < 8; ++i) {
                acc[i][0] = fma(ar[i], b0, acc[i][0]);
                acc[i][1] = fma(ar[i], b1, acc[i][1]);
                acc[i][2] = fma(ar[i], b2, acc[i][2]);
                acc[i][3] = fma(ar[i], b3, acc[i][3]);
            }
        }
        __syncthreads();
    }

    const float* bp = bias + n0 + (tx << 2);
    double bb[4] = {(double)bp[0], (double)bp[1], (double)bp[2], (double)bp[3]};
    #pragma unroll
    for (int i = 0; i < 8; ++i) {
        int row = m0 + (ty << 3) + i;
        #pragma unroll
        for (int j = 0; j < 4; ++j) {
            double v = acc[i][j] + bb[j];
            if (ACT) v = v > 0.0 ? v : 0.0;
            C[(size_t)row * N + n0 + (tx << 2) + j] = (TC)v;
        }
    }
}

// ---------------------------------------------------------------------------
// Encoder: hidden64 = relu(features[4096,20] @ w_enc[20,768] + b_enc)
// ---------------------------------------------------------------------------
__global__ __launch_bounds__(256) void encoder_kernel(
    const float* __restrict__ feats, const float* __restrict__ w,
    const float* __restrict__ b, double* __restrict__ out)
{
    __shared__ float f[20];
    const int row = blockIdx.x;
    const int t = threadIdx.x;
    if (t < 20) f[t] = feats[(size_t)row * 20 + t];
    __syncthreads();
    #pragma unroll
    for (int j = 0; j < 3; ++j) {
        int col = t + (j << 8);
        double s = (double)b[col];
        #pragma unroll
        for (int k = 0; k < 20; ++k) s += (double)f[k] * (double)w[k * H + col];
        out[(size_t)row * H + col] = s > 0.0 ? s : 0.0;
    }
}

// ---------------------------------------------------------------------------
// Attention — VERBATIM round-14 (passing; bitwise round-7 compute).
// ---------------------------------------------------------------------------
__global__ __launch_bounds__(256) void attn_kernel(
    const float* __restrict__ qkv, float* __restrict__ ctx)
{
    const int bid = blockIdx.x;
    const int qt = bid & 31;
    const int h  = (bid >> 5) & 7;
    const int b  = bid >> 8;
    const int q0 = qt * 16;
    const int t  = threadIdx.x;

    __shared__ float Qs[16][98];     //  6.3 KB (pad 98)
    __shared__ float KVs[32][100];   // 12.8 KB
    __shared__ float Ss[16][528];    // 33.8 KB (pad 528)

    const size_t base = ((size_t)b * SEQ) * (3 * H) + h * DHEAD;

    for (int i = t; i < 16 * 96; i += 256) {
        int r = i / 96, d = i % 96;
        Qs[r][d] = qkv[base + (size_t)(q0 + r) * (3 * H) + d];
    }
    __syncthreads();

    const int r  = t >> 4;
    const int kk = t & 15;
    const double scale = 0.10206207261596575;  // 1/sqrt(96)

    for (int kt = 0; kt < SEQ; kt += 32) {
        for (int i = t; i < 32 * 96; i += 256) {
            int rr = i / 96, d = i % 96;
            KVs[rr][d] = qkv[base + H + (size_t)(kt + rr) * (3 * H) + d];
        }
        __syncthreads();
        double s0 = 0.0, s1 = 0.0;
        #pragma unroll
        for (int d = 0; d < 96; d += 2) {
            float2 qf = *(const float2*)&Qs[r][d];
            float2 ka = *(const float2*)&KVs[kk][d];
            float2 kb = *(const float2*)&KVs[kk + 16][d];
            double qx = (double)qf.x, qy = (double)qf.y;
            s0 = fma(qx, (double)ka.x, s0); s0 = fma(qy, (double)ka.y, s0);
            s1 = fma(qx, (double)kb.x, s1); s1 = fma(qy, (double)kb.y, s1);
        }
        Ss[r][kt + kk]      = (float)(s0 * scale);
        Ss[r][kt + kk + 16] = (float)(s1 * scale);
        __syncthreads();
    }

    float mx = -1e30f;
    for (int j = 0; j < 32; ++j) mx = fmaxf(mx, Ss[r][kk + 16 * j]);
    #pragma unroll
    for (int o = 1; o < 16; o <<= 1) mx = fmaxf(mx, __shfl_xor(mx, o));
    double sum = 0.0;
    for (int j = 0; j < 32; ++j) {
        double e = exp((double)Ss[r][kk + 16 * j] - (double)mx);
        Ss[r][kk + 16 * j] = (float)e;
        sum += e;
    }
    #pragma unroll
    for (int o = 1; o < 16; o <<= 1) sum += __shfl_xor(sum, o);
    const double inv = 1.0 / sum;

    const int dd = kk * 6;
    double acc[6] = {};
    for (int kt = 0; kt < SEQ; kt += 32) {
        __syncthreads();
        for (int i = t; i < 32 * 96; i += 256) {
            int rr = i / 96, d = i % 96;
            KVs[rr][d] = qkv[base + 2 * H + (size_t)(kt + rr) * (3 * H) + d];
        }
        __syncthreads();
        for (int k = 0; k < 32; ++k) {
            double p = (double)Ss[r][kt + k];
            float2 v0 = *(const float2*)&KVs[k][dd];
            float2 v1 = *(const float2*)&KVs[k][dd + 2];
            float2 v2 = *(const float2*)&KVs[k][dd + 4];
            acc[0] = fma(p, (double)v0.x, acc[0]);
            acc[1] = fma(p, (double)v0.y, acc[1]);
            acc[2] = fma(p, (double)v1.x, acc[2]);
            acc[3] = fma(p, (double)v1.y, acc[3]);
            acc[4] = fma(p, (double)v2.x, acc[4]);
            acc[5] = fma(p, (double)v2.y, acc[5]);
        }
    }
    float* crow = ctx + ((size_t)(b * SEQ + q0 + r)) * H + h * DHEAD + dd;
    #pragma unroll
    for (int j = 0; j < 6; ++j) crow[j] = (float)(acc[j] * inv);
}

// ---------------------------------------------------------------------------
// hidden64 = LayerNorm(hidden64 + x64) * g + b   (all f64)
// ---------------------------------------------------------------------------
__global__ __launch_bounds__(256) void add_ln_kernel(
    double* __restrict__ hid, const double* __restrict__ x,
    const float* __restrict__ g, const float* __restrict__ bb)
{
    __shared__ double red[4];
    const int row = blockIdx.x;
    const int t = threadIdx.x;
    const size_t off = (size_t)row * H;

    double v[3]; double s = 0.0;
    #pragma unroll
    for (int j = 0; j < 3; ++j) {
        int c = t + (j << 8);
        v[j] = hid[off + c] + x[off + c];
        s += v[j];
    }
    #pragma unroll
    for (int o = 1; o < 64; o <<= 1) s += __shfl_xor(s, o);
    if ((t & 63) == 0) red[t >> 6] = s;
    __syncthreads();
    const double mu = (red[0] + red[1] + red[2] + red[3]) * (1.0 / H);
    __syncthreads();

    double q = 0.0;
    #pragma unroll
    for (int j = 0; j < 3; ++j) { double d = v[j] - mu; q += d * d; }
    #pragma unroll
    for (int o = 1; o < 64; o <<= 1) q += __shfl_xor(q, o);
    if ((t & 63) == 0) red[t >> 6] = q;
    __syncthreads();
    const double var = (red[0] + red[1] + red[2] + red[3]) * (1.0 / H);
    const double inv = 1.0 / sqrt(var + 1e-5);

    #pragma unroll
    for (int j = 0; j < 3; ++j) {
        int c = t + (j << 8);
        hid[off + c] = (v[j] - mu) * inv * (double)g[c] + (double)bb[c];
    }
}

// ---------------------------------------------------------------------------
// angles64 = t2[4096,768](f32) @ wa2[768,3] + ba2, f64 accumulate/store
// ---------------------------------------------------------------------------
__global__ __launch_bounds__(64) void angles_kernel(
    const float* __restrict__ T2, const float* __restrict__ wa2,
    const float* __restrict__ ba2, double* __restrict__ out)
{
    const int row = blockIdx.x;
    const int lane = threadIdx.x;
    const float* trow = T2 + (size_t)row * H;
    double p0 = 0.0, p1 = 0.0, p2 = 0.0;
    for (int d = lane; d < H; d += 64) {
        double v = (double)trow[d];
        p0 += v * (double)wa2[d * 3 + 0];
        p1 += v * (double)wa2[d * 3 + 1];
        p2 += v * (double)wa2[d * 3 + 2];
    }
    #pragma unroll
    for (int o = 1; o < 64; o <<= 1) {
        p0 += __shfl_xor(p0, o); p1 += __shfl_xor(p1, o); p2 += __shfl_xor(p2, o);
    }
    if (lane == 0) {
        out[(size_t)row * 3 + 0] = p0 + (double)ba2[0];
        out[(size_t)row * 3 + 1] = p1 + (double)ba2[1];
        out[(size_t)row * 3 + 2] = p2 + (double)ba2[2];
    }
}

// ---------------------------------------------------------------------------
// Sequential coordinate build — VERBATIM rounds 7/13/14 (passing): STRICT
// float32, non-fused IEEE ops, left-to-right order, fp32 carry, IN-LOOP trig
// via (float)cos((double)x). One thread per batch.
// ---------------------------------------------------------------------------
__device__ __forceinline__ float cr_cosf(float x) { return (float)cos((double)x); }
__device__ __forceinline__ float cr_sinf(float x) { return (float)sin((double)x); }

__global__ void coords_kernel(const float* __restrict__ dist,
                              const float* __restrict__ ang,
                              float* __restrict__ out)
{
    const int b = threadIdx.x;
    if (b >= BATCH) return;

    const double ba = 2.0943951023931953;   // deg2rad(120)
    const float c2x = (float)(3.8 + 3.8 * cos(ba));
    const float c2y = (float)(3.8 * sin(ba));

    float p1[3] = {c2x, c2y, 0.f};
    float p2[3] = {3.8f, 0.f, 0.f};
    float p3[3] = {0.f, 0.f, 0.f};
    float* ob = out + (size_t)b * SEQ * 3;
    ob[0] = 0.f;  ob[1] = 0.f;  ob[2] = 0.f;
    ob[3] = 3.8f; ob[4] = 0.f;  ob[5] = 0.f;
    ob[6] = c2x;  ob[7] = c2y;  ob[8] = 0.f;

    for (int i = 3; i < SEQ; ++i) {
        float r  = dist[((size_t)(b * SEQ) + i) * H + (i - 1)];
        float th = ang[((size_t)(b * SEQ) + i) * 3 + 1];
        float ch = ang[((size_t)(b * SEQ) + i) * 3 + 2];

        float e1x = __fsub_rn(p1[0], p2[0]);
        float e1y = __fsub_rn(p1[1], p2[1]);
        float e1z = __fsub_rn(p1[2], p2[2]);
        float n = __fsqrt_rn(__fadd_rn(__fadd_rn(__fmul_rn(e1x, e1x),
                 __fmul_rn(e1y, e1y)), __fmul_rn(e1z, e1z)));
        e1x = __fdiv_rn(e1x, n); e1y = __fdiv_rn(e1y, n); e1z = __fdiv_rn(e1z, n);

        float ux = __fsub_rn(p3[0], p2[0]);
        float uy = __fsub_rn(p3[1], p2[1]);
        float uz = __fsub_rn(p3[2], p2[2]);
        n = __fsqrt_rn(__fadd_rn(__fadd_rn(__fmul_rn(ux, ux),
            __fmul_rn(uy, uy)), __fmul_rn(uz, uz)));
        ux = __fdiv_rn(ux, n); uy = __fdiv_rn(uy, n); uz = __fdiv_rn(uz, n);

        float e3x = __fsub_rn(__fmul_rn(e1y, uz), __fmul_rn(e1z, uy));
        float e3y = __fsub_rn(__fmul_rn(e1z, ux), __fmul_rn(e1x, uz));
        float e3z = __fsub_rn(__fmul_rn(e1x, uy), __fmul_rn(e1y, ux));
        n = __fsqrt_rn(__fadd_rn(__fadd_rn(__fmul_rn(e3x, e3x),
            __fmul_rn(e3y, e3y)), __fmul_rn(e3z, e3z)));
        e3x = __fdiv_rn(e3x, n); e3y = __fdiv_rn(e3y, n); e3z = __fdiv_rn(e3z, n);

        float e2x = __fsub_rn(__fmul_rn(e3y, e1z), __fmul_rn(e3z, e1y));
        float e2y = __fsub_rn(__fmul_rn(e3z, e1x), __fmul_rn(e3x, e1z));
        float e2z = __fsub_rn(__fmul_rn(e3x, e1y), __fmul_rn(e3y, e1x));

        float ct = cr_cosf(th), st = cr_sinf(th);
        float cc = cr_cosf(ch), sc = cr_sinf(ch);
        float A   = __fmul_rn(r, ct);
        float rst = __fmul_rn(r, st);
        float Bc  = __fmul_rn(rst, cc);
        float Cc  = __fmul_rn(rst, sc);

        float px = __fadd_rn(__fadd_rn(__fadd_rn(p1[0], __fmul_rn(A, e1x)),
                   __fmul_rn(Bc, e2x)), __fmul_rn(Cc, e3x));
        float py = __fadd_rn(__fadd_rn(__fadd_rn(p1[1], __fmul_rn(A, e1y)),
                   __fmul_rn(Bc, e2y)), __fmul_rn(Cc, e3y));
        float pz = __fadd_rn(__fadd_rn(__fadd_rn(p1[2], __fmul_rn(A, e1z)),
                   __fmul_rn(Bc, e2z)), __fmul_rn(Cc, e3z));

        float* op = ob + (size_t)i * 3;
        op[0] = px; op[1] = py; op[2] = pz;
        p3[0] = p2[0]; p3[1] = p2[1]; p3[2] = p2[2];
        p2[0] = p1[0]; p2[1] = p1[1]; p2[2] = p1[2];
        p1[0] = px;    p1[1] = py;    p1[2] = pz;
    }
}

// ---------------------------------------------------------------------------
__global__ void cast64to32_kernel(const double* __restrict__ src,
                                  float* __restrict__ dst, size_t n)
{
    size_t i = (size_t)blockIdx.x * blockDim.x + threadIdx.x;
    size_t stride = (size_t)gridDim.x * blockDim.x;
    for (; i < n; i += stride) dst[i] = (float)src[i];
}

// ---------------------------------------------------------------------------
extern "C" void kernel_launch(void* const* d_in, const int* in_sizes, int n_in,
                              void* d_out, int out_size, void* d_ws, size_t ws_size,
                              hipStream_t stream)
{
    const float* features = (const float*)d_in[0];
    const float* w_enc = (const float*)d_in[1];
    const float* b_enc = (const float*)d_in[2];
    const float* wqkv  = (const float*)d_in[3];
    const float* bqkv  = (const float*)d_in[4];
    const float* wo    = (const float*)d_in[5];
    const float* bo    = (const float*)d_in[6];
    const float* ln1_g = (const float*)d_in[7];
    const float* ln1_b = (const float*)d_in[8];
    const float* w1    = (const float*)d_in[9];
    const float* b1    = (const float*)d_in[10];
    const float* w2    = (const float*)d_in[11];
    const float* b2    = (const float*)d_in[12];
    const float* ln2_g = (const float*)d_in[13];
    const float* ln2_b = (const float*)d_in[14];
    const float* wd1   = (const float*)d_in[15];
    const float* bd1   = (const float*)d_in[16];
    const float* wd2   = (const float*)d_in[17];
    const float* bd2   = (const float*)d_in[18];
    const float* wa1   = (const float*)d_in[19];
    const float* ba1   = (const float*)d_in[20];
    const float* wa2   = (const float*)d_in[21];
    const float* ba2   = (const float*)d_in[22];

    // workspace: hidden64 | tmp64 | dist64 | ang64 | bigF | ctxF  (round-7 layout)
    char* wp = (char*)d_ws;
    double* hidden64 = (double*)wp;                       wp += (size_t)NTOK * H * 8;
    double* tmp64    = (double*)wp;                       wp += (size_t)NTOK * H * 8;
    double* dist64   = (double*)wp;                       wp += (size_t)NTOK * H * 8;
    double* ang64    = (double*)wp;                       wp += (size_t)NTOK * 3 * 8;
    float*  bigF     = (float*)wp;                        wp += (size_t)NTOK * FFDIM * 4;
    float*  ctxF     = (float*)wp;

    float* out_dist   = (float*)d_out;                       // [B,S,H]
    float* out_ang    = out_dist + (size_t)NTOK * H;         // [B,S,3]
    float* out_coord  = out_ang + (size_t)NTOK * 3;          // [B,S,3]
    float* out_hidden = out_coord + (size_t)NTOK * 3;        // [B,S,H]

    encoder_kernel<<<NTOK, 256, 0, stream>>>(features, w_enc, b_enc, hidden64);

    for (int l = 0; l < NLAYERS; ++l) {
        gemm64<double, float, 0><<<dim3(3 * H / 64, NTOK / 128), 256, 0, stream>>>(
            hidden64, wqkv + (size_t)l * H * 3 * H, bqkv + (size_t)l * 3 * H,
            bigF, NTOK, 3 * H, H);
        attn_kernel<<<BATCH * NHEADS * (SEQ / 16), 256, 0, stream>>>(bigF, ctxF);
        gemm64<float, double, 0><<<dim3(H / 64, NTOK / 128), 256, 0, stream>>>(
            ctxF, wo + (size_t)l * H * H, bo + (size_t)l * H, tmp64, NTOK, H, H);
        add_ln_kernel<<<NTOK, 256, 0, stream>>>(hidden64, tmp64,
            ln1_g + (size_t)l * H, ln1_b + (size_t)l * H);
        gemm64<double, float, 1><<<dim3(FFDIM / 64, NTOK / 128), 256, 0, stream>>>(
            hidden64, w1 + (size_t)l * H * FFDIM, b1 + (size_t)l * FFDIM,
            bigF, NTOK, FFDIM, H);
        gemm64<float, double, 0><<<dim3(H / 64, NTOK / 128), 256, 0, stream>>>(
            bigF, w2 + (size_t)l * FFDIM * H, b2 + (size_t)l * H, tmp64, NTOK, H, FFDIM);
        add_ln_kernel<<<NTOK, 256, 0, stream>>>(hidden64, tmp64,
            ln2_g + (size_t)l * H, ln2_b + (size_t)l * H);
    }

    // distances head
    gemm64<double, float, 1><<<dim3(H / 64, NTOK / 128), 256, 0, stream>>>(
        hidden64, wd1, bd1, ctxF, NTOK, H, H);
    gemm64<float, double, 0><<<dim3(H / 64, NTOK / 128), 256, 0, stream>>>(
        ctxF, wd2, bd2, dist64, NTOK, H, H);
    // angles head
    gemm64<double, float, 1><<<dim3(H / 64, NTOK / 128), 256, 0, stream>>>(
        hidden64, wa1, ba1, ctxF, NTOK, H, H);
    angles_kernel<<<NTOK, 64, 0, stream>>>(ctxF, wa2, ba2, ang64);

    // fp32 outputs first; coords consumes those exact fp32 values (in-loop trig)
    cast64to32_kernel<<<2048, 256, 0, stream>>>(dist64, out_dist, (size_t)NTOK * H);
    cast64to32_kernel<<<48, 256, 0, stream>>>(ang64, out_ang, (size_t)NTOK * 3);
    coords_kernel<<<1, 64, 0, stream>>>(out_dist, out_ang, out_coord);
    cast64to32_kernel<<<2048, 256, 0, stream>>>(hidden64, out_hidden, (size_t)NTOK * H);
}

// Round 17
// 23799.147 us; speedup vs baseline: 1.0986x; 1.0647x over previous
//
#include <hip/hip_runtime.h>
#include <math.h>

#define H 768
#define SEQ 512
#define BATCH 8
#define NHEADS 8
#define DHEAD 96
#define FFDIM 3072
#define NLAYERS 12
#define NTOK (BATCH*SEQ)   // 4096

template<typename T> struct vec2;
template<> struct vec2<double> { using type = double2; };
template<> struct vec2<float>  { using type = float2;  };

// ---------------------------------------------------------------------------
// Tiled GEMM BM=128 — VERBATIM round-15 (passing, bit-exact f64 chain).
// BM=128, BN=64, BK=32, 256 thr, 8x4 micro-tile.
// ---------------------------------------------------------------------------
template<typename TA, typename TC, int ACT>
__global__ __launch_bounds__(256) void gemm64(
    const TA* __restrict__ A, const float* __restrict__ W,
    const float* __restrict__ bias, TC* __restrict__ C,
    int M, int N, int K)
{
    __shared__ double As[32][128];   // 32 KB
    __shared__ float  Bs[32][64];    //  8 KB

    const int m0 = blockIdx.y * 128;
    const int n0 = blockIdx.x * 64;
    const int t  = threadIdx.x;
    const int tx = t & 15;
    const int ty = t >> 4;

    const int sr2 = t >> 2;          // staging row base 0..63
    const int sc2 = t & 3;           // staging k-segment 0..3 (8 elems each)

    const int bk  = t >> 4;
    const int bnq = t & 15;

    using TA2 = typename vec2<TA>::type;

    double acc[8][4];
    #pragma unroll
    for (int i = 0; i < 8; ++i)
        #pragma unroll
        for (int j = 0; j < 4; ++j) acc[i][j] = 0.0;

    for (int k0 = 0; k0 < K; k0 += 32) {
        #pragma unroll
        for (int i = 0; i < 2; ++i) {
            int m = sr2 + (i << 6);
            const TA* src = A + (size_t)(m0 + m) * K + k0 + (sc2 << 3);
            #pragma unroll
            for (int j = 0; j < 4; ++j) {
                TA2 v = *(const TA2*)(src + (j << 1));
                As[(sc2 << 3) + (j << 1) + 0][m] = (double)v.x;
                As[(sc2 << 3) + (j << 1) + 1][m] = (double)v.y;
            }
        }
        *(float4*)&Bs[bk][bnq << 2] =
            *(const float4*)(W + (size_t)(k0 + bk) * N + n0 + (bnq << 2));
        *(float4*)&Bs[bk + 16][bnq << 2] =
            *(const float4*)(W + (size_t)(k0 + bk + 16) * N + n0 + (bnq << 2));
        __syncthreads();

        #pragma unroll
        for (int k = 0; k < 32; ++k) {
            double ar[8];
            #pragma unroll
            for (int j = 0; j < 4; ++j)
                *(double2*)&ar[j << 1] = *(const double2*)&As[k][(ty << 3) + (j << 1)];
            float4 bf = *(const float4*)&Bs[k][tx << 2];
            double b0 = (double)bf.x, b1 = (double)bf.y;
            double b2 = (double)bf.z, b3 = (double)bf.w;
            #pragma unroll
            for (int i = 0; i < 8; ++i) {
                acc[i][0] = fma(ar[i], b0, acc[i][0]);
                acc[i][1] = fma(ar[i], b1, acc[i][1]);
                acc[i][2] = fma(ar[i], b2, acc[i][2]);
                acc[i][3] = fma(ar[i], b3, acc[i][3]);
            }
        }
        __syncthreads();
    }

    const float* bp = bias + n0 + (tx << 2);
    double bb[4] = {(double)bp[0], (double)bp[1], (double)bp[2], (double)bp[3]};
    #pragma unroll
    for (int i = 0; i < 8; ++i) {
        int row = m0 + (ty << 3) + i;
        #pragma unroll
        for (int j = 0; j < 4; ++j) {
            double v = acc[i][j] + bb[j];
            if (ACT) v = v > 0.0 ? v : 0.0;
            C[(size_t)row * N + n0 + (tx << 2) + j] = (TC)v;
        }
    }
}

// ---------------------------------------------------------------------------
// Tiled GEMM BM=64 — for N=768 GEMMs (wo/ff2/heads): 768 blocks instead of
// 384 -> 6 blocks/CU. SAME per-element f64 fma chain (k ascending, identical
// promotions) => outputs bit-identical to gemm64; only thread->element
// ownership changes. BM=64, BN=64, BK=32, 256 thr, 4x4 micro-tile.
// LDS: As double[32][66] (16.9 KB) + Bs float[32][64] (8 KB).
// ---------------------------------------------------------------------------
template<typename TA, typename TC, int ACT>
__global__ __launch_bounds__(256) void gemm64_m64(
    const TA* __restrict__ A, const float* __restrict__ W,
    const float* __restrict__ bias, TC* __restrict__ C,
    int M, int N, int K)
{
    __shared__ double As[32][66];
    __shared__ float  Bs[32][64];

    const int m0 = blockIdx.y * 64;
    const int n0 = blockIdx.x * 64;
    const int t  = threadIdx.x;
    const int tx = t & 15;           // n group (4 cols)
    const int ty = t >> 4;           // m group (4 consecutive rows: ty*4+i)

    const int sr = t >> 2;           // staging row 0..63
    const int sc = (t & 3) << 3;     // staging k offset 0,8,16,24

    const int bk  = t >> 4;
    const int bnq = t & 15;

    double acc[4][4];
    #pragma unroll
    for (int i = 0; i < 4; ++i)
        #pragma unroll
        for (int j = 0; j < 4; ++j) acc[i][j] = 0.0;

    for (int k0 = 0; k0 < K; k0 += 32) {
        {
            const TA* src = A + (size_t)(m0 + sr) * K + k0 + sc;
            #pragma unroll
            for (int j = 0; j < 8; ++j)
                As[sc + j][sr] = (double)src[j];
        }
        *(float4*)&Bs[bk][bnq << 2] =
            *(const float4*)(W + (size_t)(k0 + bk) * N + n0 + (bnq << 2));
        *(float4*)&Bs[bk + 16][bnq << 2] =
            *(const float4*)(W + (size_t)(k0 + bk + 16) * N + n0 + (bnq << 2));
        __syncthreads();

        #pragma unroll
        for (int k = 0; k < 32; ++k) {
            double ar[4];
            #pragma unroll
            for (int j = 0; j < 2; ++j)
                *(double2*)&ar[j << 1] = *(const double2*)&As[k][(ty << 2) + (j << 1)];
            float4 bf = *(const float4*)&Bs[k][tx << 2];
            double b0 = (double)bf.x, b1 = (double)bf.y;
            double b2 = (double)bf.z, b3 = (double)bf.w;
            #pragma unroll
            for (int i = 0; i < 4; ++i) {
                acc[i][0] = fma(ar[i], b0, acc[i][0]);
                acc[i][1] = fma(ar[i], b1, acc[i][1]);
                acc[i][2] = fma(ar[i], b2, acc[i][2]);
                acc[i][3] = fma(ar[i], b3, acc[i][3]);
            }
        }
        __syncthreads();
    }

    const float* bp = bias + n0 + (tx << 2);
    double bb[4] = {(double)bp[0], (double)bp[1], (double)bp[2], (double)bp[3]};
    #pragma unroll
    for (int i = 0; i < 4; ++i) {
        int row = m0 + (ty << 2) + i;
        #pragma unroll
        for (int j = 0; j < 4; ++j) {
            double v = acc[i][j] + bb[j];
            if (ACT) v = v > 0.0 ? v : 0.0;
            C[(size_t)row * N + n0 + (tx << 2) + j] = (TC)v;
        }
    }
}

// ---------------------------------------------------------------------------
// Encoder: hidden64 = relu(features[4096,20] @ w_enc + b_enc)  (R15 verbatim)
// ---------------------------------------------------------------------------
__global__ __launch_bounds__(256) void encoder_kernel(
    const float* __restrict__ feats, const float* __restrict__ w,
    const float* __restrict__ b, double* __restrict__ out)
{
    __shared__ float f[20];
    const int row = blockIdx.x;
    const int t = threadIdx.x;
    if (t < 20) f[t] = feats[(size_t)row * 20 + t];
    __syncthreads();
    #pragma unroll
    for (int j = 0; j < 3; ++j) {
        int col = t + (j << 8);
        double s = (double)b[col];
        #pragma unroll
        for (int k = 0; k < 20; ++k) s += (double)f[k] * (double)w[k * H + col];
        out[(size_t)row * H + col] = s > 0.0 ? s : 0.0;
    }
}

// ---------------------------------------------------------------------------
// Attention — VERBATIM rounds 13/14/15 (passing).
// ---------------------------------------------------------------------------
__global__ __launch_bounds__(256) void attn_kernel(
    const float* __restrict__ qkv, float* __restrict__ ctx)
{
    const int bid = blockIdx.x;
    const int qt = bid & 31;
    const int h  = (bid >> 5) & 7;
    const int b  = bid >> 8;
    const int q0 = qt * 16;
    const int t  = threadIdx.x;

    __shared__ float Qs[16][98];
    __shared__ float KVs[32][100];
    __shared__ float Ss[16][528];

    const size_t base = ((size_t)b * SEQ) * (3 * H) + h * DHEAD;

    for (int i = t; i < 16 * 96; i += 256) {
        int r = i / 96, d = i % 96;
        Qs[r][d] = qkv[base + (size_t)(q0 + r) * (3 * H) + d];
    }
    __syncthreads();

    const int r  = t >> 4;
    const int kk = t & 15;
    const double scale = 0.10206207261596575;  // 1/sqrt(96)

    for (int kt = 0; kt < SEQ; kt += 32) {
        for (int i = t; i < 32 * 96; i += 256) {
            int rr = i / 96, d = i % 96;
            KVs[rr][d] = qkv[base + H + (size_t)(kt + rr) * (3 * H) + d];
        }
        __syncthreads();
        double s0 = 0.0, s1 = 0.0;
        #pragma unroll
        for (int d = 0; d < 96; d += 2) {
            float2 qf = *(const float2*)&Qs[r][d];
            float2 ka = *(const float2*)&KVs[kk][d];
            float2 kb = *(const float2*)&KVs[kk + 16][d];
            double qx = (double)qf.x, qy = (double)qf.y;
            s0 = fma(qx, (double)ka.x, s0); s0 = fma(qy, (double)ka.y, s0);
            s1 = fma(qx, (double)kb.x, s1); s1 = fma(qy, (double)kb.y, s1);
        }
        Ss[r][kt + kk]      = (float)(s0 * scale);
        Ss[r][kt + kk + 16] = (float)(s1 * scale);
        __syncthreads();
    }

    float mx = -1e30f;
    for (int j = 0; j < 32; ++j) mx = fmaxf(mx, Ss[r][kk + 16 * j]);
    #pragma unroll
    for (int o = 1; o < 16; o <<= 1) mx = fmaxf(mx, __shfl_xor(mx, o));
    double sum = 0.0;
    for (int j = 0; j < 32; ++j) {
        double e = exp((double)Ss[r][kk + 16 * j] - (double)mx);
        Ss[r][kk + 16 * j] = (float)e;
        sum += e;
    }
    #pragma unroll
    for (int o = 1; o < 16; o <<= 1) sum += __shfl_xor(sum, o);
    const double inv = 1.0 / sum;

    const int dd = kk * 6;
    double acc[6] = {};
    for (int kt = 0; kt < SEQ; kt += 32) {
        __syncthreads();
        for (int i = t; i < 32 * 96; i += 256) {
            int rr = i / 96, d = i % 96;
            KVs[rr][d] = qkv[base + 2 * H + (size_t)(kt + rr) * (3 * H) + d];
        }
        __syncthreads();
        for (int k = 0; k < 32; ++k) {
            double p = (double)Ss[r][kt + k];
            float2 v0 = *(const float2*)&KVs[k][dd];
            float2 v1 = *(const float2*)&KVs[k][dd + 2];
            float2 v2 = *(const float2*)&KVs[k][dd + 4];
            acc[0] = fma(p, (double)v0.x, acc[0]);
            acc[1] = fma(p, (double)v0.y, acc[1]);
            acc[2] = fma(p, (double)v1.x, acc[2]);
            acc[3] = fma(p, (double)v1.y, acc[3]);
            acc[4] = fma(p, (double)v2.x, acc[4]);
            acc[5] = fma(p, (double)v2.y, acc[5]);
        }
    }
    float* crow = ctx + ((size_t)(b * SEQ + q0 + r)) * H + h * DHEAD + dd;
    #pragma unroll
    for (int j = 0; j < 6; ++j) crow[j] = (float)(acc[j] * inv);
}

// ---------------------------------------------------------------------------
// hidden64 = LayerNorm(hidden64 + x64) * g + b   (all f64) — R15 verbatim
// ---------------------------------------------------------------------------
__global__ __launch_bounds__(256) void add_ln_kernel(
    double* __restrict__ hid, const double* __restrict__ x,
    const float* __restrict__ g, const float* __restrict__ bb)
{
    __shared__ double red[4];
    const int row = blockIdx.x;
    const int t = threadIdx.x;
    const size_t off = (size_t)row * H;

    double v[3]; double s = 0.0;
    #pragma unroll
    for (int j = 0; j < 3; ++j) {
        int c = t + (j << 8);
        v[j] = hid[off + c] + x[off + c];
        s += v[j];
    }
    #pragma unroll
    for (int o = 1; o < 64; o <<= 1) s += __shfl_xor(s, o);
    if ((t & 63) == 0) red[t >> 6] = s;
    __syncthreads();
    const double mu = (red[0] + red[1] + red[2] + red[3]) * (1.0 / H);
    __syncthreads();

    double q = 0.0;
    #pragma unroll
    for (int j = 0; j < 3; ++j) { double d = v[j] - mu; q += d * d; }
    #pragma unroll
    for (int o = 1; o < 64; o <<= 1) q += __shfl_xor(q, o);
    if ((t & 63) == 0) red[t >> 6] = q;
    __syncthreads();
    const double var = (red[0] + red[1] + red[2] + red[3]) * (1.0 / H);
    const double inv = 1.0 / sqrt(var + 1e-5);

    #pragma unroll
    for (int j = 0; j < 3; ++j) {
        int c = t + (j << 8);
        hid[off + c] = (v[j] - mu) * inv * (double)g[c] + (double)bb[c];
    }
}

// ---------------------------------------------------------------------------
// angles64 = t2 @ wa2 + ba2, f64 accumulate/store — R15 verbatim
// ---------------------------------------------------------------------------
__global__ __launch_bounds__(64) void angles_kernel(
    const float* __restrict__ T2, const float* __restrict__ wa2,
    const float* __restrict__ ba2, double* __restrict__ out)
{
    const int row = blockIdx.x;
    const int lane = threadIdx.x;
    const float* trow = T2 + (size_t)row * H;
    double p0 = 0.0, p1 = 0.0, p2 = 0.0;
    for (int d = lane; d < H; d += 64) {
        double v = (double)trow[d];
        p0 += v * (double)wa2[d * 3 + 0];
        p1 += v * (double)wa2[d * 3 + 1];
        p2 += v * (double)wa2[d * 3 + 2];
    }
    #pragma unroll
    for (int o = 1; o < 64; o <<= 1) {
        p0 += __shfl_xor(p0, o); p1 += __shfl_xor(p1, o); p2 += __shfl_xor(p2, o);
    }
    if (lane == 0) {
        out[(size_t)row * 3 + 0] = p0 + (double)ba2[0];
        out[(size_t)row * 3 + 1] = p1 + (double)ba2[1];
        out[(size_t)row * 3 + 2] = p2 + (double)ba2[2];
    }
}

// ---------------------------------------------------------------------------
// Sequential coordinate build — VERBATIM rounds 5/7/13/14/15 (passing).
// ---------------------------------------------------------------------------
__device__ __forceinline__ float cr_cosf(float x) { return (float)cos((double)x); }
__device__ __forceinline__ float cr_sinf(float x) { return (float)sin((double)x); }

__global__ void coords_kernel(const float* __restrict__ dist,
                              const float* __restrict__ ang,
                              float* __restrict__ out)
{
    const int b = threadIdx.x;
    if (b >= BATCH) return;

    const double ba = 2.0943951023931953;   // deg2rad(120)
    const float c2x = (float)(3.8 + 3.8 * cos(ba));
    const float c2y = (float)(3.8 * sin(ba));

    float p1[3] = {c2x, c2y, 0.f};
    float p2[3] = {3.8f, 0.f, 0.f};
    float p3[3] = {0.f, 0.f, 0.f};
    float* ob = out + (size_t)b * SEQ * 3;
    ob[0] = 0.f;  ob[1] = 0.f;  ob[2] = 0.f;
    ob[3] = 3.8f; ob[4] = 0.f;  ob[5] = 0.f;
    ob[6] = c2x;  ob[7] = c2y;  ob[8] = 0.f;

    for (int i = 3; i < SEQ; ++i) {
        float r  = dist[((size_t)(b * SEQ) + i) * H + (i - 1)];
        float th = ang[((size_t)(b * SEQ) + i) * 3 + 1];
        float ch = ang[((size_t)(b * SEQ) + i) * 3 + 2];

        float e1x = __fsub_rn(p1[0], p2[0]);
        float e1y = __fsub_rn(p1[1], p2[1]);
        float e1z = __fsub_rn(p1[2], p2[2]);
        float n = __fsqrt_rn(__fadd_rn(__fadd_rn(__fmul_rn(e1x, e1x),
                 __fmul_rn(e1y, e1y)), __fmul_rn(e1z, e1z)));
        e1x = __fdiv_rn(e1x, n); e1y = __fdiv_rn(e1y, n); e1z = __fdiv_rn(e1z, n);

        float ux = __fsub_rn(p3[0], p2[0]);
        float uy = __fsub_rn(p3[1], p2[1]);
        float uz = __fsub_rn(p3[2], p2[2]);
        n = __fsqrt_rn(__fadd_rn(__fadd_rn(__fmul_rn(ux, ux),
            __fmul_rn(uy, uy)), __fmul_rn(uz, uz)));
        ux = __fdiv_rn(ux, n); uy = __fdiv_rn(uy, n); uz = __fdiv_rn(uz, n);

        float e3x = __fsub_rn(__fmul_rn(e1y, uz), __fmul_rn(e1z, uy));
        float e3y = __fsub_rn(__fmul_rn(e1z, ux), __fmul_rn(e1x, uz));
        float e3z = __fsub_rn(__fmul_rn(e1x, uy), __fmul_rn(e1y, ux));
        n = __fsqrt_rn(__fadd_rn(__fadd_rn(__fmul_rn(e3x, e3x),
            __fmul_rn(e3y, e3y)), __fmul_rn(e3z, e3z)));
        e3x = __fdiv_rn(e3x, n); e3y = __fdiv_rn(e3y, n); e3z = __fdiv_rn(e3z, n);

        float e2x = __fsub_rn(__fmul_rn(e3y, e1z), __fmul_rn(e3z, e1y));
        float e2y = __fsub_rn(__fmul_rn(e3z, e1x), __fmul_rn(e3x, e1z));
        float e2z = __fsub_rn(__fmul_rn(e3x, e1y), __fmul_rn(e3y, e1x));

        float ct = cr_cosf(th), st = cr_sinf(th);
        float cc = cr_cosf(ch), sc = cr_sinf(ch);
        float A   = __fmul_rn(r, ct);
        float rst = __fmul_rn(r, st);
        float Bc  = __fmul_rn(rst, cc);
        float Cc  = __fmul_rn(rst, sc);

        float px = __fadd_rn(__fadd_rn(__fadd_rn(p1[0], __fmul_rn(A, e1x)),
                   __fmul_rn(Bc, e2x)), __fmul_rn(Cc, e3x));
        float py = __fadd_rn(__fadd_rn(__fadd_rn(p1[1], __fmul_rn(A, e1y)),
                   __fmul_rn(Bc, e2y)), __fmul_rn(Cc, e3y));
        float pz = __fadd_rn(__fadd_rn(__fadd_rn(p1[2], __fmul_rn(A, e1z)),
                   __fmul_rn(Bc, e2z)), __fmul_rn(Cc, e3z));

        float* op = ob + (size_t)i * 3;
        op[0] = px; op[1] = py; op[2] = pz;
        p3[0] = p2[0]; p3[1] = p2[1]; p3[2] = p2[2];
        p2[0] = p1[0]; p2[1] = p1[1]; p2[2] = p1[2];
        p1[0] = px;    p1[1] = py;    p1[2] = pz;
    }
}

// ---------------------------------------------------------------------------
__global__ void cast64to32_kernel(const double* __restrict__ src,
                                  float* __restrict__ dst, size_t n)
{
    size_t i = (size_t)blockIdx.x * blockDim.x + threadIdx.x;
    size_t stride = (size_t)gridDim.x * blockDim.x;
    for (; i < n; i += stride) dst[i] = (float)src[i];
}

// ---------------------------------------------------------------------------
extern "C" void kernel_launch(void* const* d_in, const int* in_sizes, int n_in,
                              void* d_out, int out_size, void* d_ws, size_t ws_size,
                              hipStream_t stream)
{
    const float* features = (const float*)d_in[0];
    const float* w_enc = (const float*)d_in[1];
    const float* b_enc = (const float*)d_in[2];
    const float* wqkv  = (const float*)d_in[3];
    const float* bqkv  = (const float*)d_in[4];
    const float* wo    = (const float*)d_in[5];
    const float* bo    = (const float*)d_in[6];
    const float* ln1_g = (const float*)d_in[7];
    const float* ln1_b = (const float*)d_in[8];
    const float* w1    = (const float*)d_in[9];
    const float* b1    = (const float*)d_in[10];
    const float* w2    = (const float*)d_in[11];
    const float* b2    = (const float*)d_in[12];
    const float* ln2_g = (const float*)d_in[13];
    const float* ln2_b = (const float*)d_in[14];
    const float* wd1   = (const float*)d_in[15];
    const float* bd1   = (const float*)d_in[16];
    const float* wd2   = (const float*)d_in[17];
    const float* bd2   = (const float*)d_in[18];
    const float* wa1   = (const float*)d_in[19];
    const float* ba1   = (const float*)d_in[20];
    const float* wa2   = (const float*)d_in[21];
    const float* ba2   = (const float*)d_in[22];

    // workspace: hidden64 | tmp64 | dist64 | ang64 | bigF | ctxF  (R15 layout)
    char* wp = (char*)d_ws;
    double* hidden64 = (double*)wp;                       wp += (size_t)NTOK * H * 8;
    double* tmp64    = (double*)wp;                       wp += (size_t)NTOK * H * 8;
    double* dist64   = (double*)wp;                       wp += (size_t)NTOK * H * 8;
    double* ang64    = (double*)wp;                       wp += (size_t)NTOK * 3 * 8;
    float*  bigF     = (float*)wp;                        wp += (size_t)NTOK * FFDIM * 4;
    float*  ctxF     = (float*)wp;

    float* out_dist   = (float*)d_out;                       // [B,S,H]
    float* out_ang    = out_dist + (size_t)NTOK * H;         // [B,S,3]
    float* out_coord  = out_ang + (size_t)NTOK * 3;          // [B,S,3]
    float* out_hidden = out_coord + (size_t)NTOK * 3;        // [B,S,H]

    encoder_kernel<<<NTOK, 256, 0, stream>>>(features, w_enc, b_enc, hidden64);

    for (int l = 0; l < NLAYERS; ++l) {
        gemm64<double, float, 0><<<dim3(3 * H / 64, NTOK / 128), 256, 0, stream>>>(
            hidden64, wqkv + (size_t)l * H * 3 * H, bqkv + (size_t)l * 3 * H,
            bigF, NTOK, 3 * H, H);
        attn_kernel<<<BATCH * NHEADS * (SEQ / 16), 256, 0, stream>>>(bigF, ctxF);
        gemm64_m64<float, double, 0><<<dim3(H / 64, NTOK / 64), 256, 0, stream>>>(
            ctxF, wo + (size_t)l * H * H, bo + (size_t)l * H, tmp64, NTOK, H, H);
        add_ln_kernel<<<NTOK, 256, 0, stream>>>(hidden64, tmp64,
            ln1_g + (size_t)l * H, ln1_b + (size_t)l * H);
        gemm64<double, float, 1><<<dim3(FFDIM / 64, NTOK / 128), 256, 0, stream>>>(
            hidden64, w1 + (size_t)l * H * FFDIM, b1 + (size_t)l * FFDIM,
            bigF, NTOK, FFDIM, H);
        gemm64_m64<float, double, 0><<<dim3(H / 64, NTOK / 64), 256, 0, stream>>>(
            bigF, w2 + (size_t)l * FFDIM * H, b2 + (size_t)l * H, tmp64, NTOK, H, FFDIM);
        add_ln_kernel<<<NTOK, 256, 0, stream>>>(hidden64, tmp64,
            ln2_g + (size_t)l * H, ln2_b + (size_t)l * H);
    }

    // distances head
    gemm64_m64<double, float, 1><<<dim3(H / 64, NTOK / 64), 256, 0, stream>>>(
        hidden64, wd1, bd1, ctxF, NTOK, H, H);
    gemm64_m64<float, double, 0><<<dim3(H / 64, NTOK / 64), 256, 0, stream>>>(
        ctxF, wd2, bd2, dist64, NTOK, H, H);
    // angles head
    gemm64_m64<double, float, 1><<<dim3(H / 64, NTOK / 64), 256, 0, stream>>>(
        hidden64, wa1, ba1, ctxF, NTOK, H, H);
    angles_kernel<<<NTOK, 64, 0, stream>>>(ctxF, wa2, ba2, ang64);

    // fp32 outputs first; coords consumes those exact fp32 values
    cast64to32_kernel<<<2048, 256, 0, stream>>>(dist64, out_dist, (size_t)NTOK * H);
    cast64to32_kernel<<<48, 256, 0, stream>>>(ang64, out_ang, (size_t)NTOK * 3);
    coords_kernel<<<1, 64, 0, stream>>>(out_dist, out_ang, out_coord);
    cast64to32_kernel<<<2048, 256, 0, stream>>>(hidden64, out_hidden, (size_t)NTOK * H);
}

// Round 18
// 23708.420 us; speedup vs baseline: 1.1028x; 1.0038x over previous
//
#include <hip/hip_runtime.h>
#include <math.h>

#define H 768
#define SEQ 512
#define BATCH 8
#define NHEADS 8
#define DHEAD 96
#define FFDIM 3072
#define NLAYERS 12
#define NTOK (BATCH*SEQ)   // 4096

template<typename T> struct vec2;
template<> struct vec2<double> { using type = double2; };
template<> struct vec2<float>  { using type = float2;  };

// ---------------------------------------------------------------------------
// Tiled GEMM BM=128 — compute VERBATIM rounds 15/17 (passing, bit-exact f64
// chain). Only change: 1-D grid with XCD-banded decode (xcd = bb&7 owns a
// contiguous 4-m-tile band; A-band 3.1 MB stays L2-resident per XCD; W
// re-reads absorbed by L3). Pure index remap — zero numerics impact.
// Grid = 32 * (N/64).  BM=128, BN=64, BK=32, 256 thr, 8x4 micro-tile.
// ---------------------------------------------------------------------------
template<typename TA, typename TC, int ACT>
__global__ __launch_bounds__(256) void gemm64(
    const TA* __restrict__ A, const float* __restrict__ W,
    const float* __restrict__ bias, TC* __restrict__ C,
    int M, int N, int K)
{
    __shared__ double As[32][128];   // 32 KB
    __shared__ float  Bs[32][64];    //  8 KB

    const int bb  = blockIdx.x;
    const int xcd = bb & 7;
    const int i0  = bb >> 3;
    const int mb  = (xcd << 2) | (i0 & 3);   // 32 m-tiles: band of 4 per XCD
    const int nt  = i0 >> 2;
    const int m0  = mb << 7;
    const int n0  = nt << 6;

    const int t  = threadIdx.x;
    const int tx = t & 15;
    const int ty = t >> 4;

    const int sr2 = t >> 2;          // staging row base 0..63
    const int sc2 = t & 3;           // staging k-segment 0..3 (8 elems each)

    const int bk  = t >> 4;
    const int bnq = t & 15;

    using TA2 = typename vec2<TA>::type;

    double acc[8][4];
    #pragma unroll
    for (int i = 0; i < 8; ++i)
        #pragma unroll
        for (int j = 0; j < 4; ++j) acc[i][j] = 0.0;

    for (int k0 = 0; k0 < K; k0 += 32) {
        #pragma unroll
        for (int i = 0; i < 2; ++i) {
            int m = sr2 + (i << 6);
            const TA* src = A + (size_t)(m0 + m) * K + k0 + (sc2 << 3);
            #pragma unroll
            for (int j = 0; j < 4; ++j) {
                TA2 v = *(const TA2*)(src + (j << 1));
                As[(sc2 << 3) + (j << 1) + 0][m] = (double)v.x;
                As[(sc2 << 3) + (j << 1) + 1][m] = (double)v.y;
            }
        }
        *(float4*)&Bs[bk][bnq << 2] =
            *(const float4*)(W + (size_t)(k0 + bk) * N + n0 + (bnq << 2));
        *(float4*)&Bs[bk + 16][bnq << 2] =
            *(const float4*)(W + (size_t)(k0 + bk + 16) * N + n0 + (bnq << 2));
        __syncthreads();

        #pragma unroll
        for (int k = 0; k < 32; ++k) {
            double ar[8];
            #pragma unroll
            for (int j = 0; j < 4; ++j)
                *(double2*)&ar[j << 1] = *(const double2*)&As[k][(ty << 3) + (j << 1)];
            float4 bf = *(const float4*)&Bs[k][tx << 2];
            double b0 = (double)bf.x, b1 = (double)bf.y;
            double b2 = (double)bf.z, b3 = (double)bf.w;
            #pragma unroll
            for (int i = 0; i < 8; ++i) {
                acc[i][0] = fma(ar[i], b0, acc[i][0]);
                acc[i][1] = fma(ar[i], b1, acc[i][1]);
                acc[i][2] = fma(ar[i], b2, acc[i][2]);
                acc[i][3] = fma(ar[i], b3, acc[i][3]);
            }
        }
        __syncthreads();
    }

    const float* bp = bias + n0 + (tx << 2);
    double bb4[4] = {(double)bp[0], (double)bp[1], (double)bp[2], (double)bp[3]};
    #pragma unroll
    for (int i = 0; i < 8; ++i) {
        int row = m0 + (ty << 3) + i;
        #pragma unroll
        for (int j = 0; j < 4; ++j) {
            double v = acc[i][j] + bb4[j];
            if (ACT) v = v > 0.0 ? v : 0.0;
            C[(size_t)row * N + n0 + (tx << 2) + j] = (TC)v;
        }
    }
}

// ---------------------------------------------------------------------------
// Tiled GEMM BM=64 — compute VERBATIM round-17 (passing). XCD-banded 1-D
// grid decode (8 m-tiles per XCD). Grid = 64 * (N/64).
// ---------------------------------------------------------------------------
template<typename TA, typename TC, int ACT>
__global__ __launch_bounds__(256) void gemm64_m64(
    const TA* __restrict__ A, const float* __restrict__ W,
    const float* __restrict__ bias, TC* __restrict__ C,
    int M, int N, int K)
{
    __shared__ double As[32][66];
    __shared__ float  Bs[32][64];

    const int bb  = blockIdx.x;
    const int xcd = bb & 7;
    const int i0  = bb >> 3;
    const int mb  = (xcd << 3) | (i0 & 7);   // 64 m-tiles: band of 8 per XCD
    const int nt  = i0 >> 3;
    const int m0  = mb << 6;
    const int n0  = nt << 6;

    const int t  = threadIdx.x;
    const int tx = t & 15;
    const int ty = t >> 4;

    const int sr = t >> 2;
    const int sc = (t & 3) << 3;

    const int bk  = t >> 4;
    const int bnq = t & 15;

    double acc[4][4];
    #pragma unroll
    for (int i = 0; i < 4; ++i)
        #pragma unroll
        for (int j = 0; j < 4; ++j) acc[i][j] = 0.0;

    for (int k0 = 0; k0 < K; k0 += 32) {
        {
            const TA* src = A + (size_t)(m0 + sr) * K + k0 + sc;
            #pragma unroll
            for (int j = 0; j < 8; ++j)
                As[sc + j][sr] = (double)src[j];
        }
        *(float4*)&Bs[bk][bnq << 2] =
            *(const float4*)(W + (size_t)(k0 + bk) * N + n0 + (bnq << 2));
        *(float4*)&Bs[bk + 16][bnq << 2] =
            *(const float4*)(W + (size_t)(k0 + bk + 16) * N + n0 + (bnq << 2));
        __syncthreads();

        #pragma unroll
        for (int k = 0; k < 32; ++k) {
            double ar[4];
            #pragma unroll
            for (int j = 0; j < 2; ++j)
                *(double2*)&ar[j << 1] = *(const double2*)&As[k][(ty << 2) + (j << 1)];
            float4 bf = *(const float4*)&Bs[k][tx << 2];
            double b0 = (double)bf.x, b1 = (double)bf.y;
            double b2 = (double)bf.z, b3 = (double)bf.w;
            #pragma unroll
            for (int i = 0; i < 4; ++i) {
                acc[i][0] = fma(ar[i], b0, acc[i][0]);
                acc[i][1] = fma(ar[i], b1, acc[i][1]);
                acc[i][2] = fma(ar[i], b2, acc[i][2]);
                acc[i][3] = fma(ar[i], b3, acc[i][3]);
            }
        }
        __syncthreads();
    }

    const float* bp = bias + n0 + (tx << 2);
    double bb4[4] = {(double)bp[0], (double)bp[1], (double)bp[2], (double)bp[3]};
    #pragma unroll
    for (int i = 0; i < 4; ++i) {
        int row = m0 + (ty << 2) + i;
        #pragma unroll
        for (int j = 0; j < 4; ++j) {
            double v = acc[i][j] + bb4[j];
            if (ACT) v = v > 0.0 ? v : 0.0;
            C[(size_t)row * N + n0 + (tx << 2) + j] = (TC)v;
        }
    }
}

// ---------------------------------------------------------------------------
// Encoder: hidden64 = relu(features[4096,20] @ w_enc + b_enc)  (verbatim)
// ---------------------------------------------------------------------------
__global__ __launch_bounds__(256) void encoder_kernel(
    const float* __restrict__ feats, const float* __restrict__ w,
    const float* __restrict__ b, double* __restrict__ out)
{
    __shared__ float f[20];
    const int row = blockIdx.x;
    const int t = threadIdx.x;
    if (t < 20) f[t] = feats[(size_t)row * 20 + t];
    __syncthreads();
    #pragma unroll
    for (int j = 0; j < 3; ++j) {
        int col = t + (j << 8);
        double s = (double)b[col];
        #pragma unroll
        for (int k = 0; k < 20; ++k) s += (double)f[k] * (double)w[k * H + col];
        out[(size_t)row * H + col] = s > 0.0 ? s : 0.0;
    }
}

// ---------------------------------------------------------------------------
// Attention — VERBATIM rounds 13/14/15/17 (passing).
// ---------------------------------------------------------------------------
__global__ __launch_bounds__(256) void attn_kernel(
    const float* __restrict__ qkv, float* __restrict__ ctx)
{
    const int bid = blockIdx.x;
    const int qt = bid & 31;
    const int h  = (bid >> 5) & 7;
    const int b  = bid >> 8;
    const int q0 = qt * 16;
    const int t  = threadIdx.x;

    __shared__ float Qs[16][98];
    __shared__ float KVs[32][100];
    __shared__ float Ss[16][528];

    const size_t base = ((size_t)b * SEQ) * (3 * H) + h * DHEAD;

    for (int i = t; i < 16 * 96; i += 256) {
        int r = i / 96, d = i % 96;
        Qs[r][d] = qkv[base + (size_t)(q0 + r) * (3 * H) + d];
    }
    __syncthreads();

    const int r  = t >> 4;
    const int kk = t & 15;
    const double scale = 0.10206207261596575;  // 1/sqrt(96)

    for (int kt = 0; kt < SEQ; kt += 32) {
        for (int i = t; i < 32 * 96; i += 256) {
            int rr = i / 96, d = i % 96;
            KVs[rr][d] = qkv[base + H + (size_t)(kt + rr) * (3 * H) + d];
        }
        __syncthreads();
        double s0 = 0.0, s1 = 0.0;
        #pragma unroll
        for (int d = 0; d < 96; d += 2) {
            float2 qf = *(const float2*)&Qs[r][d];
            float2 ka = *(const float2*)&KVs[kk][d];
            float2 kb = *(const float2*)&KVs[kk + 16][d];
            double qx = (double)qf.x, qy = (double)qf.y;
            s0 = fma(qx, (double)ka.x, s0); s0 = fma(qy, (double)ka.y, s0);
            s1 = fma(qx, (double)kb.x, s1); s1 = fma(qy, (double)kb.y, s1);
        }
        Ss[r][kt + kk]      = (float)(s0 * scale);
        Ss[r][kt + kk + 16] = (float)(s1 * scale);
        __syncthreads();
    }

    float mx = -1e30f;
    for (int j = 0; j < 32; ++j) mx = fmaxf(mx, Ss[r][kk + 16 * j]);
    #pragma unroll
    for (int o = 1; o < 16; o <<= 1) mx = fmaxf(mx, __shfl_xor(mx, o));
    double sum = 0.0;
    for (int j = 0; j < 32; ++j) {
        double e = exp((double)Ss[r][kk + 16 * j] - (double)mx);
        Ss[r][kk + 16 * j] = (float)e;
        sum += e;
    }
    #pragma unroll
    for (int o = 1; o < 16; o <<= 1) sum += __shfl_xor(sum, o);
    const double inv = 1.0 / sum;

    const int dd = kk * 6;
    double acc[6] = {};
    for (int kt = 0; kt < SEQ; kt += 32) {
        __syncthreads();
        for (int i = t; i < 32 * 96; i += 256) {
            int rr = i / 96, d = i % 96;
            KVs[rr][d] = qkv[base + 2 * H + (size_t)(kt + rr) * (3 * H) + d];
        }
        __syncthreads();
        for (int k = 0; k < 32; ++k) {
            double p = (double)Ss[r][kt + k];
            float2 v0 = *(const float2*)&KVs[k][dd];
            float2 v1 = *(const float2*)&KVs[k][dd + 2];
            float2 v2 = *(const float2*)&KVs[k][dd + 4];
            acc[0] = fma(p, (double)v0.x, acc[0]);
            acc[1] = fma(p, (double)v0.y, acc[1]);
            acc[2] = fma(p, (double)v1.x, acc[2]);
            acc[3] = fma(p, (double)v1.y, acc[3]);
            acc[4] = fma(p, (double)v2.x, acc[4]);
            acc[5] = fma(p, (double)v2.y, acc[5]);
        }
    }
    float* crow = ctx + ((size_t)(b * SEQ + q0 + r)) * H + h * DHEAD + dd;
    #pragma unroll
    for (int j = 0; j < 6; ++j) crow[j] = (float)(acc[j] * inv);
}

// ---------------------------------------------------------------------------
// hidden64 = LayerNorm(hidden64 + x64) * g + b   (all f64) — verbatim
// ---------------------------------------------------------------------------
__global__ __launch_bounds__(256) void add_ln_kernel(
    double* __restrict__ hid, const double* __restrict__ x,
    const float* __restrict__ g, const float* __restrict__ bb)
{
    __shared__ double red[4];
    const int row = blockIdx.x;
    const int t = threadIdx.x;
    const size_t off = (size_t)row * H;

    double v[3]; double s = 0.0;
    #pragma unroll
    for (int j = 0; j < 3; ++j) {
        int c = t + (j << 8);
        v[j] = hid[off + c] + x[off + c];
        s += v[j];
    }
    #pragma unroll
    for (int o = 1; o < 64; o <<= 1) s += __shfl_xor(s, o);
    if ((t & 63) == 0) red[t >> 6] = s;
    __syncthreads();
    const double mu = (red[0] + red[1] + red[2] + red[3]) * (1.0 / H);
    __syncthreads();

    double q = 0.0;
    #pragma unroll
    for (int j = 0; j < 3; ++j) { double d = v[j] - mu; q += d * d; }
    #pragma unroll
    for (int o = 1; o < 64; o <<= 1) q += __shfl_xor(q, o);
    if ((t & 63) == 0) red[t >> 6] = q;
    __syncthreads();
    const double var = (red[0] + red[1] + red[2] + red[3]) * (1.0 / H);
    const double inv = 1.0 / sqrt(var + 1e-5);

    #pragma unroll
    for (int j = 0; j < 3; ++j) {
        int c = t + (j << 8);
        hid[off + c] = (v[j] - mu) * inv * (double)g[c] + (double)bb[c];
    }
}

// ---------------------------------------------------------------------------
// angles64 = t2 @ wa2 + ba2, f64 accumulate/store — verbatim
// ---------------------------------------------------------------------------
__global__ __launch_bounds__(64) void angles_kernel(
    const float* __restrict__ T2, const float* __restrict__ wa2,
    const float* __restrict__ ba2, double* __restrict__ out)
{
    const int row = blockIdx.x;
    const int lane = threadIdx.x;
    const float* trow = T2 + (size_t)row * H;
    double p0 = 0.0, p1 = 0.0, p2 = 0.0;
    for (int d = lane; d < H; d += 64) {
        double v = (double)trow[d];
        p0 += v * (double)wa2[d * 3 + 0];
        p1 += v * (double)wa2[d * 3 + 1];
        p2 += v * (double)wa2[d * 3 + 2];
    }
    #pragma unroll
    for (int o = 1; o < 64; o <<= 1) {
        p0 += __shfl_xor(p0, o); p1 += __shfl_xor(p1, o); p2 += __shfl_xor(p2, o);
    }
    if (lane == 0) {
        out[(size_t)row * 3 + 0] = p0 + (double)ba2[0];
        out[(size_t)row * 3 + 1] = p1 + (double)ba2[1];
        out[(size_t)row * 3 + 2] = p2 + (double)ba2[2];
    }
}

// ---------------------------------------------------------------------------
// Sequential coordinate build — VERBATIM rounds 5/7/13/14/15/17 (passing).
// ---------------------------------------------------------------------------
__device__ __forceinline__ float cr_cosf(float x) { return (float)cos((double)x); }
__device__ __forceinline__ float cr_sinf(float x) { return (float)sin((double)x); }

__global__ void coords_kernel(const float* __restrict__ dist,
                              const float* __restrict__ ang,
                              float* __restrict__ out)
{
    const int b = threadIdx.x;
    if (b >= BATCH) return;

    const double ba = 2.0943951023931953;   // deg2rad(120)
    const float c2x = (float)(3.8 + 3.8 * cos(ba));
    const float c2y = (float)(3.8 * sin(ba));

    float p1[3] = {c2x, c2y, 0.f};
    float p2[3] = {3.8f, 0.f, 0.f};
    float p3[3] = {0.f, 0.f, 0.f};
    float* ob = out + (size_t)b * SEQ * 3;
    ob[0] = 0.f;  ob[1] = 0.f;  ob[2] = 0.f;
    ob[3] = 3.8f; ob[4] = 0.f;  ob[5] = 0.f;
    ob[6] = c2x;  ob[7] = c2y;  ob[8] = 0.f;

    for (int i = 3; i < SEQ; ++i) {
        float r  = dist[((size_t)(b * SEQ) + i) * H + (i - 1)];
        float th = ang[((size_t)(b * SEQ) + i) * 3 + 1];
        float ch = ang[((size_t)(b * SEQ) + i) * 3 + 2];

        float e1x = __fsub_rn(p1[0], p2[0]);
        float e1y = __fsub_rn(p1[1], p2[1]);
        float e1z = __fsub_rn(p1[2], p2[2]);
        float n = __fsqrt_rn(__fadd_rn(__fadd_rn(__fmul_rn(e1x, e1x),
                 __fmul_rn(e1y, e1y)), __fmul_rn(e1z, e1z)));
        e1x = __fdiv_rn(e1x, n); e1y = __fdiv_rn(e1y, n); e1z = __fdiv_rn(e1z, n);

        float ux = __fsub_rn(p3[0], p2[0]);
        float uy = __fsub_rn(p3[1], p2[1]);
        float uz = __fsub_rn(p3[2], p2[2]);
        n = __fsqrt_rn(__fadd_rn(__fadd_rn(__fmul_rn(ux, ux),
            __fmul_rn(uy, uy)), __fmul_rn(uz, uz)));
        ux = __fdiv_rn(ux, n); uy = __fdiv_rn(uy, n); uz = __fdiv_rn(uz, n);

        float e3x = __fsub_rn(__fmul_rn(e1y, uz), __fmul_rn(e1z, uy));
        float e3y = __fsub_rn(__fmul_rn(e1z, ux), __fmul_rn(e1x, uz));
        float e3z = __fsub_rn(__fmul_rn(e1x, uy), __fmul_rn(e1y, ux));
        n = __fsqrt_rn(__fadd_rn(__fadd_rn(__fmul_rn(e3x, e3x),
            __fmul_rn(e3y, e3y)), __fmul_rn(e3z, e3z)));
        e3x = __fdiv_rn(e3x, n); e3y = __fdiv_rn(e3y, n); e3z = __fdiv_rn(e3z, n);

        float e2x = __fsub_rn(__fmul_rn(e3y, e1z), __fmul_rn(e3z, e1y));
        float e2y = __fsub_rn(__fmul_rn(e3z, e1x), __fmul_rn(e3x, e1z));
        float e2z = __fsub_rn(__fmul_rn(e3x, e1y), __fmul_rn(e3y, e1x));

        float ct = cr_cosf(th), st = cr_sinf(th);
        float cc = cr_cosf(ch), sc = cr_sinf(ch);
        float A   = __fmul_rn(r, ct);
        float rst = __fmul_rn(r, st);
        float Bc  = __fmul_rn(rst, cc);
        float Cc  = __fmul_rn(rst, sc);

        float px = __fadd_rn(__fadd_rn(__fadd_rn(p1[0], __fmul_rn(A, e1x)),
                   __fmul_rn(Bc, e2x)), __fmul_rn(Cc, e3x));
        float py = __fadd_rn(__fadd_rn(__fadd_rn(p1[1], __fmul_rn(A, e1y)),
                   __fmul_rn(Bc, e2y)), __fmul_rn(Cc, e3y));
        float pz = __fadd_rn(__fadd_rn(__fadd_rn(p1[2], __fmul_rn(A, e1z)),
                   __fmul_rn(Bc, e2z)), __fmul_rn(Cc, e3z));

        float* op = ob + (size_t)i * 3;
        op[0] = px; op[1] = py; op[2] = pz;
        p3[0] = p2[0]; p3[1] = p2[1]; p3[2] = p2[2];
        p2[0] = p1[0]; p2[1] = p1[1]; p2[2] = p1[2];
        p1[0] = px;    p1[1] = py;    p1[2] = pz;
    }
}

// ---------------------------------------------------------------------------
__global__ void cast64to32_kernel(const double* __restrict__ src,
                                  float* __restrict__ dst, size_t n)
{
    size_t i = (size_t)blockIdx.x * blockDim.x + threadIdx.x;
    size_t stride = (size_t)gridDim.x * blockDim.x;
    for (; i < n; i += stride) dst[i] = (float)src[i];
}

// ---------------------------------------------------------------------------
extern "C" void kernel_launch(void* const* d_in, const int* in_sizes, int n_in,
                              void* d_out, int out_size, void* d_ws, size_t ws_size,
                              hipStream_t stream)
{
    const float* features = (const float*)d_in[0];
    const float* w_enc = (const float*)d_in[1];
    const float* b_enc = (const float*)d_in[2];
    const float* wqkv  = (const float*)d_in[3];
    const float* bqkv  = (const float*)d_in[4];
    const float* wo    = (const float*)d_in[5];
    const float* bo    = (const float*)d_in[6];
    const float* ln1_g = (const float*)d_in[7];
    const float* ln1_b = (const float*)d_in[8];
    const float* w1    = (const float*)d_in[9];
    const float* b1    = (const float*)d_in[10];
    const float* w2    = (const float*)d_in[11];
    const float* b2    = (const float*)d_in[12];
    const float* ln2_g = (const float*)d_in[13];
    const float* ln2_b = (const float*)d_in[14];
    const float* wd1   = (const float*)d_in[15];
    const float* bd1   = (const float*)d_in[16];
    const float* wd2   = (const float*)d_in[17];
    const float* bd2   = (const float*)d_in[18];
    const float* wa1   = (const float*)d_in[19];
    const float* ba1   = (const float*)d_in[20];
    const float* wa2   = (const float*)d_in[21];
    const float* ba2   = (const float*)d_in[22];

    // workspace: hidden64 | tmp64 | dist64 | ang64 | bigF | ctxF
    char* wp = (char*)d_ws;
    double* hidden64 = (double*)wp;                       wp += (size_t)NTOK * H * 8;
    double* tmp64    = (double*)wp;                       wp += (size_t)NTOK * H * 8;
    double* dist64   = (double*)wp;                       wp += (size_t)NTOK * H * 8;
    double* ang64    = (double*)wp;                       wp += (size_t)NTOK * 3 * 8;
    float*  bigF     = (float*)wp;                        wp += (size_t)NTOK * FFDIM * 4;
    float*  ctxF     = (float*)wp;

    float* out_dist   = (float*)d_out;                       // [B,S,H]
    float* out_ang    = out_dist + (size_t)NTOK * H;         // [B,S,3]
    float* out_coord  = out_ang + (size_t)NTOK * 3;          // [B,S,3]
    float* out_hidden = out_coord + (size_t)NTOK * 3;        // [B,S,H]

    encoder_kernel<<<NTOK, 256, 0, stream>>>(features, w_enc, b_enc, hidden64);

    for (int l = 0; l < NLAYERS; ++l) {
        gemm64<double, float, 0><<<32 * (3 * H / 64), 256, 0, stream>>>(
            hidden64, wqkv + (size_t)l * H * 3 * H, bqkv + (size_t)l * 3 * H,
            bigF, NTOK, 3 * H, H);
        attn_kernel<<<BATCH * NHEADS * (SEQ / 16), 256, 0, stream>>>(bigF, ctxF);
        gemm64_m64<float, double, 0><<<64 * (H / 64), 256, 0, stream>>>(
            ctxF, wo + (size_t)l * H * H, bo + (size_t)l * H, tmp64, NTOK, H, H);
        add_ln_kernel<<<NTOK, 256, 0, stream>>>(hidden64, tmp64,
            ln1_g + (size_t)l * H, ln1_b + (size_t)l * H);
        gemm64<double, float, 1><<<32 * (FFDIM / 64), 256, 0, stream>>>(
            hidden64, w1 + (size_t)l * H * FFDIM, b1 + (size_t)l * FFDIM,
            bigF, NTOK, FFDIM, H);
        gemm64_m64<float, double, 0><<<64 * (H / 64), 256, 0, stream>>>(
            bigF, w2 + (size_t)l * FFDIM * H, b2 + (size_t)l * H, tmp64, NTOK, H, FFDIM);
        add_ln_kernel<<<NTOK, 256, 0, stream>>>(hidden64, tmp64,
            ln2_g + (size_t)l * H, ln2_b + (size_t)l * H);
    }

    // distances head
    gemm64_m64<double, float, 1><<<64 * (H / 64), 256, 0, stream>>>(
        hidden64, wd1, bd1, ctxF, NTOK, H, H);
    gemm64_m64<float, double, 0><<<64 * (H / 64), 256, 0, stream>>>(
        ctxF, wd2, bd2, dist64, NTOK, H, H);
    // angles head
    gemm64_m64<double, float, 1><<<64 * (H / 64), 256, 0, stream>>>(
        hidden64, wa1, ba1, ctxF, NTOK, H, H);
    angles_kernel<<<NTOK, 64, 0, stream>>>(ctxF, wa2, ba2, ang64);

    // fp32 outputs first; coords consumes those exact fp32 values
    cast64to32_kernel<<<2048, 256, 0, stream>>>(dist64, out_dist, (size_t)NTOK * H);
    cast64to32_kernel<<<48, 256, 0, stream>>>(ang64, out_ang, (size_t)NTOK * 3);
    coords_kernel<<<1, 64, 0, stream>>>(out_dist, out_ang, out_coord);
    cast64to32_kernel<<<2048, 256, 0, stream>>>(hidden64, out_hidden, (size_t)NTOK * H);
}